// Round 1
// baseline (29731.763 us; speedup 1.0000x reference)
//
#include <hip/hip_runtime.h>
#include <hip/hip_bf16.h>
#include <cstdio>

// ---------------------------------------------------------------------------
// HierarchicalDecoder: 4-layer LSTM stack, T=512, batch U=16.
// Strategy: persistent kernels + device-scope grid barrier per timestep;
// weights persisted in VGPRs as MFMA B-fragments (bf16, gate-interleaved
// permutation col' = 4*j + gate so one 16-col MFMA tile = 4 units x 4 gates).
// ---------------------------------------------------------------------------

typedef __attribute__((ext_vector_type(8))) short short8;   // 8 x bf16
typedef __attribute__((ext_vector_type(4))) float f32x4;
using bf16 = __hip_bfloat16;

__device__ __forceinline__ float bfraw2f(short s){
  return __uint_as_float(((unsigned)(unsigned short)s) << 16);
}

// ---------------- grid barrier (device-scope, sense-free monotonic gen) ----
__device__ __forceinline__ void gbar(unsigned* flags, int nwg, unsigned gen){
  __threadfence();                 // flush dirty L2 lines to coherence point
  __syncthreads();
  if (threadIdx.x == 0)
    __hip_atomic_store(&flags[blockIdx.x], gen, __ATOMIC_RELEASE, __HIP_MEMORY_SCOPE_AGENT);
  if (threadIdx.x < 64){
    const int f0 = threadIdx.x;
    for (;;){
      bool ok = true;
      for (int f = f0; f < nwg; f += 64)
        ok &= (__hip_atomic_load(&flags[f], __ATOMIC_ACQUIRE, __HIP_MEMORY_SCOPE_AGENT) >= gen);
      if (__all(ok)) break;
      __builtin_amdgcn_s_sleep(1);
    }
  }
  __syncthreads();
}

// ---------------- MFMA accumulate over concat(A1,A2) with reg-resident B ---
template<int N1, int N2>
__device__ __forceinline__ f32x4 mfma_acc(const bf16* a1, int s1,
                                          const bf16* a2, int s2, int e2off,
                                          const short8 (&breg)[32], int lane)
{
  f32x4 acc = {0.f, 0.f, 0.f, 0.f};
  const int r  = lane & 15;
  const int kg = (lane >> 4) * 8;
#pragma unroll
  for (int i = 0; i < N1; ++i){
    short8 a = *(const short8*)(a1 + (size_t)r * s1 + i * 32 + kg);
    acc = __builtin_amdgcn_mfma_f32_16x16x32_bf16(a, breg[i], acc, 0, 0, 0);
  }
#pragma unroll
  for (int i = 0; i < N2; ++i){
    short8 a = *(const short8*)(a2 + (size_t)r * s2 + e2off + i * 32 + kg);
    acc = __builtin_amdgcn_mfma_f32_16x16x32_bf16(a, breg[N1 + i], acc, 0, 0, 0);
  }
  return acc;
}

// ---------------- LSTM gate math + h/c update --------------------------------
// acc rows = u (4 per lane), col = colp = 4*j+g.  3 shuffles gather i,f,g,o.
__device__ __forceinline__ void gate_step(const f32x4& acc, const float* add,
                                          float* c_st, int g, int kg, int j,
                                          bf16* hs_t1, int Hl, float* hTp)
{
#pragma unroll
  for (int rr = 0; rr < 4; ++rr){
    float v = acc[rr] + add[rr];
    float a = (g == 2) ? tanhf(v) : 1.f / (1.f + expf(-v));
    float x1 = __shfl_xor(a, 1);
    float x2 = __shfl_xor(a, 2);
    float x3 = __shfl_xor(x1, 2);
    float cn = x1 * c_st[rr] + a * x2;    // valid on g==0 lanes: sig(f)*c + sig(i)*tanh(g)
    float hn = x3 * tanhf(cn);            // sig(o)*tanh(c)
    c_st[rr] = cn;
    if (g == 0){
      int u = kg * 4 + rr;
      hs_t1[(size_t)u * Hl + j] = __float2bfloat16(hn);
      if (hTp) hTp[(size_t)u * Hl + j] = hn;
    }
  }
}

// ---------------- weight prep: permute rows to col'=4j+g, concat K, cvt bf16 -
__global__ void k_prep_w(const float* __restrict__ srcA, const float* __restrict__ srcB,
                         int K1, int K2, int H, bf16* __restrict__ dst)
{
  const int row = blockIdx.x;            // col' in [0, 4H)
  const int j = row >> 2, g = row & 3;
  const int Kt = K1 + K2;
  const float* sA = srcA + (size_t)(g * H + j) * K1;
  const float* sB = srcB ? srcB + (size_t)(g * H + j) * K2 : nullptr;
  bf16* d = dst + (size_t)row * Kt;
  for (int k = threadIdx.x; k < Kt; k += blockDim.x)
    d[k] = __float2bfloat16(k < K1 ? sA[k] : sB[k - K1]);
}

__global__ void k_prep_b(const float* __restrict__ src, int H, float* __restrict__ dst){
  int i = blockIdx.x * blockDim.x + threadIdx.x;
  if (i < 4 * H) dst[i] = src[(i & 3) * H + (i >> 2)];
}

__global__ void k_conv_bf(const float* __restrict__ src, bf16* __restrict__ dst, int n){
  int i = blockIdx.x * blockDim.x + threadIdx.x;
  if (i < n) dst[i] = __float2bfloat16(src[i]);
}

// ---------------- fc0: x[t][u][n] = tanh(z[t][u*32:]:fc0_w[n,:] + b[n]) -----
__global__ void k_fc0(const float* __restrict__ z, const float* __restrict__ w,
                      const float* __restrict__ b, bf16* __restrict__ x)
{
  const int m = blockIdx.x;              // t*16+u
  const int t = m >> 4, u = m & 15;
  const float* zr = z + (size_t)t * 512 + u * 32;
  float zv[32];
#pragma unroll
  for (int k = 0; k < 32; ++k) zv[k] = zr[k];
  for (int n = threadIdx.x; n < 512; n += 256){
    const float* wr = w + n * 32;
    float s = b[n];
#pragma unroll
    for (int k = 0; k < 32; ++k) s += zv[k] * wr[k];
    x[(size_t)m * 512 + n] = __float2bfloat16(tanhf(s));
  }
}

// ---------------- big GEMM for gx0 = x @ Wgx0'^T + bc0' ---------------------
__device__ __forceinline__ void gload16(const void* g, void* lds_wave_base){
  __builtin_amdgcn_global_load_lds((const __attribute__((address_space(1))) void*)g,
                                   (__attribute__((address_space(3))) void*)lds_wave_base,
                                   16, 0, 0);
}

__global__ __launch_bounds__(256) void k_gemm_gx0(const bf16* __restrict__ A,
                                                  const bf16* __restrict__ W,
                                                  const float* __restrict__ bias,
                                                  float* __restrict__ C)
{
  // C[8192][2048] = A[8192][512] @ W[2048][512]^T + bias ; 128x128 tile, BK=64
  __shared__ bf16 Al[128 * 64];
  __shared__ bf16 Bl[128 * 64];
  const int tid = threadIdx.x, lane = tid & 63, wave = tid >> 6;
  const int bm = blockIdx.x & 63, bn = blockIdx.x >> 6;
  const int wm = wave >> 1, wn = wave & 1;
  const int col = lane & 15, kg = lane >> 4;

  f32x4 acc[4][4];
#pragma unroll
  for (int i = 0; i < 4; ++i)
#pragma unroll
    for (int q = 0; q < 4; ++q) acc[i][q] = f32x4{0.f, 0.f, 0.f, 0.f};

  const int r = tid >> 3, c8 = (tid & 7) * 8;
  for (int k0 = 0; k0 < 512; k0 += 64){
    const bf16* ga = A + (size_t)(bm * 128 + r) * 512 + k0 + c8;
    const bf16* gb = W + (size_t)(bn * 128 + r) * 512 + k0 + c8;
#pragma unroll
    for (int i = 0; i < 4; ++i){
      gload16(ga + (size_t)32 * i * 512, (char*)Al + (size_t)i * 4096 + wave * 1024);
      gload16(gb + (size_t)32 * i * 512, (char*)Bl + (size_t)i * 4096 + wave * 1024);
    }
    __syncthreads();
#pragma unroll
    for (int kb = 0; kb < 2; ++kb){
      short8 af[4], bfr[4];
#pragma unroll
      for (int i = 0; i < 4; ++i)
        af[i] = *(const short8*)&Al[(wm * 64 + i * 16 + col) * 64 + kb * 32 + kg * 8];
#pragma unroll
      for (int i = 0; i < 4; ++i)
        bfr[i] = *(const short8*)&Bl[(wn * 64 + i * 16 + col) * 64 + kb * 32 + kg * 8];
#pragma unroll
      for (int i = 0; i < 4; ++i)
#pragma unroll
        for (int q = 0; q < 4; ++q)
          acc[i][q] = __builtin_amdgcn_mfma_f32_16x16x32_bf16(af[i], bfr[q], acc[i][q], 0, 0, 0);
    }
    __syncthreads();
  }
#pragma unroll
  for (int i = 0; i < 4; ++i)
#pragma unroll
    for (int q = 0; q < 4; ++q){
      int cc = bn * 128 + wn * 64 + q * 16 + col;
      float bv = bias[cc];
#pragma unroll
      for (int rr = 0; rr < 4; ++rr){
        int rrow = bm * 128 + wm * 64 + i * 16 + kg * 4 + rr;
        C[(size_t)rrow * 2048 + cc] = acc[i][q][rr] + bv;
      }
    }
}

// ---------------- conductor: c0 (WG 0-31) || c1 (WG 32-63), 513 ticks -------
__global__ __launch_bounds__(256, 1) void k_cond(
    const bf16* __restrict__ Wc0, const bf16* __restrict__ Wc1,
    const float* __restrict__ bc1, const float* __restrict__ gx0,
    bf16* h0seq, bf16* h1seq, float* hT0, float* hT1, unsigned* flags)
{
  const int wg = blockIdx.x, tid = threadIdx.x;
  const int lane = tid & 63, wave = tid >> 6;
  const int layer = wg >> 5;
  const int wid = (wg & 31) * 4 + wave;           // 0..127 n-tile
  const int col = lane & 15, kg = lane >> 4;
  const int colp = wid * 16 + col;                // permuted gate col in [0,2048)
  const int j = colp >> 2, g = colp & 3;

  short8 breg[32];
  if (layer == 0){
#pragma unroll
    for (int i = 0; i < 16; ++i)
      breg[i] = *(const short8*)(Wc0 + (size_t)colp * 512 + i * 32 + kg * 8);
  } else {
#pragma unroll
    for (int i = 0; i < 32; ++i)
      breg[i] = *(const short8*)(Wc1 + (size_t)colp * 1024 + i * 32 + kg * 8);
  }
  const float bias = layer ? bc1[colp] : 0.f;
  float c_st[4] = {0.f, 0.f, 0.f, 0.f};

  for (int tick = 0; tick < 513; ++tick){
    const int t = tick - layer;
    if (t >= 0 && t < 512){
      f32x4 acc;
      float add[4];
      if (layer == 0){
        acc = mfma_acc<16, 0>(h0seq + (size_t)t * 16 * 512, 512, nullptr, 0, 0, breg, lane);
#pragma unroll
        for (int rr = 0; rr < 4; ++rr)
          add[rr] = gx0[((size_t)t * 16 + kg * 4 + rr) * 2048 + colp];
      } else {
        acc = mfma_acc<16, 16>(h0seq + (size_t)(t + 1) * 16 * 512, 512,
                               h1seq + (size_t)t * 16 * 512, 512, 0, breg, lane);
#pragma unroll
        for (int rr = 0; rr < 4; ++rr) add[rr] = bias;
      }
      bf16* hs = (layer ? h1seq : h0seq) + (size_t)(t + 1) * 16 * 512;
      float* hTp = (t == 511) ? (layer ? hT1 : hT0) : nullptr;
      gate_step(acc, add, c_st, g, kg, j, hs, 512, hTp);
    }
    gbar(flags, 64, (unsigned)(tick + 1));
  }
}

// ---------------- hd0/hd1 = tanh(fc1(hT)) into decoder seq slot 0 -----------
__global__ void k_hd(const float* __restrict__ hT0, const float* __restrict__ hT1,
                     const float* __restrict__ w, const float* __restrict__ b,
                     bf16* __restrict__ d0s0, bf16* __restrict__ d1s0)
{
  int gid = blockIdx.x * 256 + threadIdx.x;       // 32768
  int sel = gid >> 14;
  int u = (gid >> 10) & 15, n = gid & 1023;
  const float* h = (sel ? hT1 : hT0) + u * 512;
  const float* wr = w + (size_t)n * 512;
  float s = b[n];
  for (int k = 0; k < 512; ++k) s += h[k] * wr[k];
  (sel ? d1s0 : d0s0)[(size_t)u * 1024 + n] = __float2bfloat16(tanhf(s));
}

// ---------------- decoder: d0 (WG 0-127) || d1 (WG 128-255), 513 ticks ------
// Each 16-col tile is split across a wave pair (K-split), combined via LDS.
__global__ __launch_bounds__(256, 1) void k_dec(
    const bf16* __restrict__ Wd0, const bf16* __restrict__ Wd1,
    const float* __restrict__ bd0, const float* __restrict__ bd1,
    const bf16* __restrict__ h1seq, bf16* d0seq, bf16* d1seq, unsigned* flags)
{
  const int wg = blockIdx.x, tid = threadIdx.x;
  const int lane = tid & 63, wave = tid >> 6;
  const int layer = wg >> 7;
  const int pairi = (wg & 127) * 2 + (wave >> 1); // 0..255 n-tile
  const int half = wave & 1;
  const int col = lane & 15, kg = lane >> 4;
  const int colp = pairi * 16 + col;              // [0,4096)
  const int j = colp >> 2, g = colp & 3;
  __shared__ f32x4 part[2][64];

  short8 breg[32];
  if (layer == 0){
    const bf16* W = Wd0 + (size_t)colp * 1536 + half * 768;
#pragma unroll
    for (int i = 0; i < 24; ++i) breg[i] = *(const short8*)(W + i * 32 + kg * 8);
  } else {
    const bf16* W = Wd1 + (size_t)colp * 2048 + half * 1024;
#pragma unroll
    for (int i = 0; i < 32; ++i) breg[i] = *(const short8*)(W + i * 32 + kg * 8);
  }
  const float bias = layer ? bd1[colp] : bd0[colp];
  float c_st[4] = {0.f, 0.f, 0.f, 0.f};

  for (int tick = 0; tick < 513; ++tick){
    const int t = tick - layer;
    const bool active = (t >= 0 && t < 512);
    f32x4 acc;
    if (active){
      if (layer == 0){
        const bf16* a1 = h1seq + (size_t)(t + 1) * 16 * 512;   // input = h1s[t]
        const bf16* a2 = d0seq + (size_t)t * 16 * 1024;        // own h (slot t)
        if (half == 0) acc = mfma_acc<16, 8>(a1, 512, a2, 1024, 0, breg, lane);
        else           acc = mfma_acc<0, 24>(nullptr, 0, a2, 1024, 256, breg, lane);
      } else {
        const bf16* a1 = d0seq + (size_t)(t + 1) * 16 * 1024;  // input = d0s[t]
        const bf16* a2 = d1seq + (size_t)t * 16 * 1024;        // own h
        if (half == 0) acc = mfma_acc<32, 0>(a1, 1024, nullptr, 0, 0, breg, lane);
        else           acc = mfma_acc<0, 32>(nullptr, 0, a2, 1024, 0, breg, lane);
      }
      if (half == 1) part[wave >> 1][lane] = acc;
    }
    __syncthreads();
    if (active && half == 0){
      f32x4 p2 = part[wave >> 1][lane];
      float add[4];
#pragma unroll
      for (int rr = 0; rr < 4; ++rr) add[rr] = p2[rr] + bias;
      bf16* hs = (layer ? d1seq : d0seq) + (size_t)(t + 1) * 16 * 1024;
      gate_step(acc, add, c_st, g, kg, j, hs, 1024, nullptr);
    }
    gbar(flags, 256, (unsigned)(tick + 1));
  }
}

// ---------------- logits[u][o][t] = d1s[t][u]:out_w[o] + out_b[o] -----------
__global__ __launch_bounds__(256) void k_logits(const bf16* __restrict__ d1seq,
                                                const bf16* __restrict__ ow,
                                                const float* __restrict__ ob,
                                                float* __restrict__ logits)
{
  const int u = blockIdx.x >> 4, tb = blockIdx.x & 15;
  __shared__ bf16 rows[32][1024];
  const int tid = threadIdx.x;
  for (int idx = tid; idx < 4096; idx += 256){
    int tl = idx >> 7, seg = idx & 127;
    *(short8*)&rows[tl][seg * 8] =
      *(const short8*)(d1seq + ((size_t)(tb * 32 + tl + 1) * 16 + u) * 1024 + seg * 8);
  }
  __syncthreads();
  for (int p = tid; p < 512; p += 256){
    int tl = p >> 4, o = p & 15;
    const bf16* wr = ow + (size_t)o * 1024;
    float s = 0.f;
    for (int k = 0; k < 1024; k += 8){
      short8 av = *(const short8*)&rows[tl][k];
      short8 wv = *(const short8*)(wr + k);
#pragma unroll
      for (int e = 0; e < 8; ++e) s += bfraw2f(av[e]) * bfraw2f(wv[e]);
    }
    logits[((size_t)u * 16 + o) * 512 + tb * 32 + tl] = s + ob[o];
  }
}

// ---------------- softmax over t per (u,o); out[t][u*16+o] ------------------
__global__ __launch_bounds__(256) void k_softmax(const float* __restrict__ logits,
                                                 float* __restrict__ out)
{
  const int u = blockIdx.x >> 4, o = blockIdx.x & 15;
  const float* L = logits + ((size_t)u * 16 + o) * 512;
  const int tid = threadIdx.x;
  float v0 = L[tid], v1 = L[tid + 256];
  float m = fmaxf(v0, v1);
  for (int d = 1; d < 64; d <<= 1) m = fmaxf(m, __shfl_xor(m, d));
  __shared__ float red[4], red2[4];
  if ((tid & 63) == 0) red[tid >> 6] = m;
  __syncthreads();
  m = fmaxf(fmaxf(red[0], red[1]), fmaxf(red[2], red[3]));
  float e0 = expf(v0 - m), e1 = expf(v1 - m);
  float s = e0 + e1;
  for (int d = 1; d < 64; d <<= 1) s += __shfl_xor(s, d);
  if ((tid & 63) == 0) red2[tid >> 6] = s;
  __syncthreads();
  s = red2[0] + red2[1] + red2[2] + red2[3];
  float inv = 1.f / s;
  out[(size_t)tid * 256 + u * 16 + o] = e0 * inv;
  out[(size_t)(tid + 256) * 256 + u * 16 + o] = e1 * inv;
}

// ---------------------------------------------------------------------------
extern "C" void kernel_launch(void* const* d_in, const int* in_sizes, int n_in,
                              void* d_out, int out_size, void* d_ws, size_t ws_size,
                              hipStream_t stream)
{
  const float* z      = (const float*)d_in[0];
  const float* fc0_w  = (const float*)d_in[1];
  const float* fc0_b  = (const float*)d_in[2];
  const float* fc1_w  = (const float*)d_in[3];
  const float* fc1_b  = (const float*)d_in[4];
  const float* c_wih0 = (const float*)d_in[5];
  const float* c_whh0 = (const float*)d_in[6];
  const float* c_b0   = (const float*)d_in[7];
  const float* c_wih1 = (const float*)d_in[8];
  const float* c_whh1 = (const float*)d_in[9];
  const float* c_b1   = (const float*)d_in[10];
  const float* d_wih0 = (const float*)d_in[11];
  const float* d_whh0 = (const float*)d_in[12];
  const float* d_b0   = (const float*)d_in[13];
  const float* d_wih1 = (const float*)d_in[14];
  const float* d_whh1 = (const float*)d_in[15];
  const float* d_b1   = (const float*)d_in[16];
  const float* out_w  = (const float*)d_in[17];
  const float* out_b  = (const float*)d_in[18];

  char* p = (char*)d_ws;
  auto alloc = [&](size_t bytes) -> char* {
    char* r = p; p += (bytes + 255) & ~(size_t)255; return r;
  };
  bf16*  Wgx0p  = (bf16*)alloc(2048ull * 512 * 2);
  bf16*  Wc0p   = (bf16*)alloc(2048ull * 512 * 2);
  bf16*  Wc1p   = (bf16*)alloc(2048ull * 1024 * 2);
  bf16*  Wd0p   = (bf16*)alloc(4096ull * 1536 * 2);
  bf16*  Wd1p   = (bf16*)alloc(4096ull * 2048 * 2);
  float* bc0p   = (float*)alloc(2048 * 4);
  float* bc1p   = (float*)alloc(2048 * 4);
  float* bd0p   = (float*)alloc(4096 * 4);
  float* bd1p   = (float*)alloc(4096 * 4);
  bf16*  outwbf = (bf16*)alloc(16384 * 2);
  bf16*  x      = (bf16*)alloc(8192ull * 512 * 2);
  float* gx0    = (float*)alloc(8192ull * 2048 * 4);
  bf16*  h0seq  = (bf16*)alloc(513ull * 16 * 512 * 2);
  bf16*  h1seq  = (bf16*)alloc(513ull * 16 * 512 * 2);
  bf16*  d0seq  = (bf16*)alloc(513ull * 16 * 1024 * 2);
  bf16*  d1seq  = (bf16*)alloc(513ull * 16 * 1024 * 2);
  float* hT0    = (float*)alloc(16 * 512 * 4);
  float* hT1    = (float*)alloc(16 * 512 * 4);
  float* logits = (float*)alloc(16ull * 16 * 512 * 4);
  unsigned* flagsC = (unsigned*)alloc(64 * 4);
  unsigned* flagsD = (unsigned*)alloc(256 * 4);
  if ((size_t)(p - (char*)d_ws) > ws_size){
    fprintf(stderr, "kernel_launch: ws too small (%zu needed, %zu given)\n",
            (size_t)(p - (char*)d_ws), ws_size);
    return;
  }

  // zero barrier flags + initial hidden slots (slot 0 of conductor seqs)
  hipMemsetAsync(flagsC, 0, 64 * 4, stream);
  hipMemsetAsync(flagsD, 0, 256 * 4, stream);
  hipMemsetAsync(h0seq, 0, 16 * 512 * 2, stream);
  hipMemsetAsync(h1seq, 0, 16 * 512 * 2, stream);

  // weight prep (permute gate cols to 4j+g, concat [wih;whh] along K, cvt bf16)
  k_prep_w<<<2048, 256, 0, stream>>>(c_wih0, nullptr, 512, 0,   512, Wgx0p);
  k_prep_w<<<2048, 256, 0, stream>>>(c_whh0, nullptr, 512, 0,   512, Wc0p);
  k_prep_w<<<2048, 256, 0, stream>>>(c_wih1, c_whh1, 512, 512,  512, Wc1p);
  k_prep_w<<<4096, 256, 0, stream>>>(d_wih0, d_whh0, 512, 1024, 1024, Wd0p);
  k_prep_w<<<4096, 256, 0, stream>>>(d_wih1, d_whh1, 1024, 1024, 1024, Wd1p);
  k_prep_b<<<8,  256, 0, stream>>>(c_b0, 512,  bc0p);
  k_prep_b<<<8,  256, 0, stream>>>(c_b1, 512,  bc1p);
  k_prep_b<<<16, 256, 0, stream>>>(d_b0, 1024, bd0p);
  k_prep_b<<<16, 256, 0, stream>>>(d_b1, 1024, bd1p);
  k_conv_bf<<<64, 256, 0, stream>>>(out_w, outwbf, 16 * 1024);

  // fc0 + hoisted input GEMM for conductor layer 0
  k_fc0<<<8192, 256, 0, stream>>>(z, fc0_w, fc0_b, x);
  k_gemm_gx0<<<1024, 256, 0, stream>>>(x, Wgx0p, bc0p, gx0);

  // conductor (c0 || c1 pipelined, 513 ticks)
  k_cond<<<64, 256, 0, stream>>>(Wc0p, Wc1p, bc1p, gx0, h0seq, h1seq, hT0, hT1, flagsC);

  // decoder initial hiddens
  k_hd<<<128, 256, 0, stream>>>(hT0, hT1, fc1_w, fc1_b, d0seq, d1seq);

  // decoder (d0 || d1 pipelined, 513 ticks)
  k_dec<<<256, 256, 0, stream>>>(Wd0p, Wd1p, bd0p, bd1p, h1seq, d0seq, d1seq, flagsD);

  // output head
  k_logits<<<256, 256, 0, stream>>>(d1seq, outwbf, out_b, logits);
  k_softmax<<<256, 256, 0, stream>>>(logits, (float*)d_out);
}

// Round 2
// 9044.037 us; speedup vs baseline: 3.2874x; 3.2874x over previous
//
#include <hip/hip_runtime.h>
#include <hip/hip_bf16.h>
#include <cstdio>

// ---------------------------------------------------------------------------
// HierarchicalDecoder: 4-layer LSTM stack, T=512, batch U=16.
// Persistent kernels + fence-free device-scope barrier per timestep.
// Weights pinned in VGPRs (asm-laundered). Dynamic h-state exchanged via
// write-through (sc0 sc1) stores and bypass (sc0 sc1) loads -> no buffer_wbl2
// / buffer_inv anywhere in the tick loop.
// ---------------------------------------------------------------------------

typedef __attribute__((ext_vector_type(8))) short short8;   // 8 x bf16
typedef __attribute__((ext_vector_type(4))) float f32x4;
using bf16 = __hip_bfloat16;

__device__ __forceinline__ float bfraw2f(short s){
  return __uint_as_float(((unsigned)(unsigned short)s) << 16);
}

// ---- fence-free grid barrier: monotonic counter, relaxed atomics ----------
__device__ __forceinline__ void gbar_arrive(unsigned* cnt){
  asm volatile("s_waitcnt vmcnt(0)" ::: "memory");   // drain h-store acks (per wave)
  __syncthreads();                                   // all waves drained
  if (threadIdx.x == 0)
    __hip_atomic_fetch_add(cnt, 1u, __ATOMIC_RELAXED, __HIP_MEMORY_SCOPE_AGENT);
}
__device__ __forceinline__ void gbar_wait(const unsigned* cnt, unsigned target){
  if (threadIdx.x == 0){
    while (__hip_atomic_load(cnt, __ATOMIC_RELAXED, __HIP_MEMORY_SCOPE_AGENT) < target)
      __builtin_amdgcn_s_sleep(1);
  }
  __syncthreads();
}

// ---- coherent data path ----------------------------------------------------
// N x 16B loads, base+i*64B; DYN -> bypass caches (read from coherence point)
template<int N, bool DYN>
__device__ __forceinline__ void ldA(const bf16* base, short8* av){
#pragma unroll
  for (int i = 0; i < N; ++i){
    const bf16* p = base + i * 32;
    if constexpr (DYN)
      asm volatile("global_load_dwordx4 %0, %1, off sc0 sc1"
                   : "=v"(av[i]) : "v"(p) : "memory");
    else
      av[i] = *(const short8*)p;
  }
}

__device__ __forceinline__ void st2_sc1(bf16* p, unsigned v){
  asm volatile("global_store_short %0, %1, off sc0 sc1" :: "v"(p), "v"(v) : "memory");
}

// ---- LSTM gate math; lanes 4j..4j+3 hold gates i,f,g,o of unit j ----------
__device__ __forceinline__ void gates_store(const float v[4], float* c_st, int g,
                                            int kg, int j, bf16* hrow, int Hl,
                                            float* hTp)
{
#pragma unroll
  for (int rr = 0; rr < 4; ++rr){
    float a = (g == 2) ? tanhf(v[rr]) : 1.f / (1.f + expf(-v[rr]));
    float x1 = __shfl_xor(a, 1);
    float x2 = __shfl_xor(a, 2);
    float x3 = __shfl_xor(x1, 2);
    float cn = x1 * c_st[rr] + a * x2;   // on g==0 lanes: sig(f)*c + sig(i)*tanh(g)
    float hn = x3 * tanhf(cn);           // sig(o)*tanh(c)
    c_st[rr] = cn;
    if (g == 0){
      int u = kg * 4 + rr;
      bf16 hb = __float2bfloat16(hn);
      unsigned us = *reinterpret_cast<unsigned short*>(&hb);
      st2_sc1(hrow + (size_t)u * Hl + j, us);
      if (hTp) hTp[(size_t)u * Hl + j] = hn;
    }
  }
}

// ---- weight prep: permute rows to col'=4j+g, concat K, cvt bf16 ------------
__global__ void k_prep_w(const float* __restrict__ srcA, const float* __restrict__ srcB,
                         int K1, int K2, int H, bf16* __restrict__ dst)
{
  const int row = blockIdx.x;            // col' in [0, 4H)
  const int j = row >> 2, g = row & 3;
  const int Kt = K1 + K2;
  const float* sA = srcA + (size_t)(g * H + j) * K1;
  const float* sB = srcB ? srcB + (size_t)(g * H + j) * K2 : nullptr;
  bf16* d = dst + (size_t)row * Kt;
  for (int k = threadIdx.x; k < Kt; k += blockDim.x)
    d[k] = __float2bfloat16(k < K1 ? sA[k] : sB[k - K1]);
}

__global__ void k_prep_b(const float* __restrict__ src, int H, float* __restrict__ dst){
  int i = blockIdx.x * blockDim.x + threadIdx.x;
  if (i < 4 * H) dst[i] = src[(i & 3) * H + (i >> 2)];
}

__global__ void k_conv_bf(const float* __restrict__ src, bf16* __restrict__ dst, int n){
  int i = blockIdx.x * blockDim.x + threadIdx.x;
  if (i < n) dst[i] = __float2bfloat16(src[i]);
}

// ---- fc0 -------------------------------------------------------------------
__global__ void k_fc0(const float* __restrict__ z, const float* __restrict__ w,
                      const float* __restrict__ b, bf16* __restrict__ x)
{
  const int m = blockIdx.x;              // t*16+u
  const int t = m >> 4, u = m & 15;
  const float* zr = z + (size_t)t * 512 + u * 32;
  float zv[32];
#pragma unroll
  for (int k = 0; k < 32; ++k) zv[k] = zr[k];
  for (int n = threadIdx.x; n < 512; n += 256){
    const float* wr = w + n * 32;
    float s = b[n];
#pragma unroll
    for (int k = 0; k < 32; ++k) s += zv[k] * wr[k];
    x[(size_t)m * 512 + n] = __float2bfloat16(tanhf(s));
  }
}

// ---- big GEMM for gx0 = x @ Wgx0'^T + bc0' ---------------------------------
__device__ __forceinline__ void gload16(const void* g, void* lds_wave_base){
  __builtin_amdgcn_global_load_lds((const __attribute__((address_space(1))) void*)g,
                                   (__attribute__((address_space(3))) void*)lds_wave_base,
                                   16, 0, 0);
}

__global__ __launch_bounds__(256) void k_gemm_gx0(const bf16* __restrict__ A,
                                                  const bf16* __restrict__ W,
                                                  const float* __restrict__ bias,
                                                  float* __restrict__ C)
{
  __shared__ bf16 Al[128 * 64];
  __shared__ bf16 Bl[128 * 64];
  const int tid = threadIdx.x, lane = tid & 63, wave = tid >> 6;
  const int bm = blockIdx.x & 63, bn = blockIdx.x >> 6;
  const int wm = wave >> 1, wn = wave & 1;
  const int col = lane & 15, kg = lane >> 4;

  f32x4 acc[4][4];
#pragma unroll
  for (int i = 0; i < 4; ++i)
#pragma unroll
    for (int q = 0; q < 4; ++q) acc[i][q] = f32x4{0.f, 0.f, 0.f, 0.f};

  const int r = tid >> 3, c8 = (tid & 7) * 8;
  for (int k0 = 0; k0 < 512; k0 += 64){
    const bf16* ga = A + (size_t)(bm * 128 + r) * 512 + k0 + c8;
    const bf16* gb = W + (size_t)(bn * 128 + r) * 512 + k0 + c8;
#pragma unroll
    for (int i = 0; i < 4; ++i){
      gload16(ga + (size_t)32 * i * 512, (char*)Al + (size_t)i * 4096 + wave * 1024);
      gload16(gb + (size_t)32 * i * 512, (char*)Bl + (size_t)i * 4096 + wave * 1024);
    }
    __syncthreads();
#pragma unroll
    for (int kb = 0; kb < 2; ++kb){
      short8 af[4], bfr[4];
#pragma unroll
      for (int i = 0; i < 4; ++i)
        af[i] = *(const short8*)&Al[(wm * 64 + i * 16 + col) * 64 + kb * 32 + kg * 8];
#pragma unroll
      for (int i = 0; i < 4; ++i)
        bfr[i] = *(const short8*)&Bl[(wn * 64 + i * 16 + col) * 64 + kb * 32 + kg * 8];
#pragma unroll
      for (int i = 0; i < 4; ++i)
#pragma unroll
        for (int q = 0; q < 4; ++q)
          acc[i][q] = __builtin_amdgcn_mfma_f32_16x16x32_bf16(af[i], bfr[q], acc[i][q], 0, 0, 0);
    }
    __syncthreads();
  }
#pragma unroll
  for (int i = 0; i < 4; ++i)
#pragma unroll
    for (int q = 0; q < 4; ++q){
      int cc = bn * 128 + wn * 64 + q * 16 + col;
      float bv = bias[cc];
#pragma unroll
      for (int rr = 0; rr < 4; ++rr){
        int rrow = bm * 128 + wm * 64 + i * 16 + kg * 4 + rr;
        C[(size_t)rrow * 2048 + cc] = acc[i][q][rr] + bv;
      }
    }
}

// ---- conductor: L0 = WG 0-15 (1 wave/tile), L1 = WG 16-47 (wave pairs) -----
__global__ __launch_bounds__(512, 2) void k_cond(
    const bf16* __restrict__ Wc0, const bf16* __restrict__ Wc1,
    const float* __restrict__ bc1, const float* __restrict__ gx0,
    bf16* h0seq, bf16* h1seq, float* hT0, float* hT1, unsigned* cnt)
{
  const int wg = blockIdx.x, tid = threadIdx.x;
  const int lane = tid & 63, wave = tid >> 6;
  const int col = lane & 15, kg = lane >> 4;
  const int r = col;                         // batch row (u) for the A operand
  const bool L0 = wg < 16;
  __shared__ f32x4 part[4][64];

  int tileIdx, half = 0;
  if (L0) tileIdx = wg * 8 + wave;                       // [0,128)
  else  { tileIdx = (wg - 16) * 4 + (wave >> 1); half = wave & 1; }
  const int colp = tileIdx * 16 + col;                   // [0,2048)
  const int j = colp >> 2, g = colp & 3;

  short8 breg[16];
  {
    const bf16* W = L0 ? (Wc0 + (size_t)colp * 512)
                       : (Wc1 + (size_t)colp * 1024 + half * 512);
#pragma unroll
    for (int i = 0; i < 16; ++i) breg[i] = *(const short8*)(W + i * 32 + kg * 8);
  }
#pragma unroll
  for (int i = 0; i < 16; ++i) asm volatile("" : "+v"(breg[i]));   // pin in VGPRs

  const float bias = L0 ? 0.f : bc1[colp];
  float c_st[4] = {0.f, 0.f, 0.f, 0.f};
  float gxv[4];
  if (L0){
#pragma unroll
    for (int rr = 0; rr < 4; ++rr)
      gxv[rr] = gx0[((size_t)(kg * 4 + rr)) * 2048 + colp];        // t = 0
  }

  for (int tick = 0; tick < 513; ++tick){
    const int t = tick - (L0 ? 0 : 1);
    const bool active = (t >= 0 && t < 512);
    f32x4 acc = {0.f, 0.f, 0.f, 0.f};
    if (active){
      short8 av[16];
      const bf16* base;
      if (L0)             base = h0seq + (size_t)t * 16 * 512 + r * 512 + kg * 8;
      else if (half == 0) base = h0seq + (size_t)(t + 1) * 16 * 512 + r * 512 + kg * 8;
      else                base = h1seq + (size_t)t * 16 * 512 + r * 512 + kg * 8;
      ldA<16, true>(base, av);
      asm volatile("s_waitcnt vmcnt(0)" ::: "memory");
      __builtin_amdgcn_sched_barrier(0);
#pragma unroll
      for (int i = 0; i < 16; ++i)
        acc = __builtin_amdgcn_mfma_f32_16x16x32_bf16(av[i], breg[i], acc, 0, 0, 0);
      if (!L0 && half == 1) part[wave >> 1][lane] = acc;
    }
    if (!L0) __syncthreads();                            // uniform per WG
    if (active && (L0 || half == 0)){
      float v[4];
      if (L0){
#pragma unroll
        for (int rr = 0; rr < 4; ++rr) v[rr] = acc[rr] + gxv[rr];  // gx0 has bias
      } else {
        f32x4 p2 = part[wave >> 1][lane];
#pragma unroll
        for (int rr = 0; rr < 4; ++rr) v[rr] = acc[rr] + p2[rr] + bias;
      }
      bf16* hrow = (L0 ? h0seq : h1seq) + (size_t)(t + 1) * 16 * 512;
      float* hTp = (t == 511) ? (L0 ? hT0 : hT1) : nullptr;
      gates_store(v, c_st, g, kg, j, hrow, 512, hTp);
    }
    gbar_arrive(cnt);
    if (L0 && tick + 1 < 512){                           // prefetch gx0 for next t
#pragma unroll
      for (int rr = 0; rr < 4; ++rr)
        gxv[rr] = gx0[((size_t)(tick + 1) * 16 + kg * 4 + rr) * 2048 + colp];
    }
    gbar_wait(cnt, 48u * (tick + 1));
  }
}

// ---- hd0/hd1 = tanh(fc1(hT)) into decoder seq slot 0 -----------------------
__global__ void k_hd(const float* __restrict__ hT0, const float* __restrict__ hT1,
                     const float* __restrict__ w, const float* __restrict__ b,
                     bf16* __restrict__ d0s0, bf16* __restrict__ d1s0)
{
  int gid = blockIdx.x * 256 + threadIdx.x;       // 32768
  int sel = gid >> 14;
  int u = (gid >> 10) & 15, n = gid & 1023;
  const float* h = (sel ? hT1 : hT0) + u * 512;
  const float* wr = w + (size_t)n * 512;
  float s = b[n];
  for (int k = 0; k < 512; ++k) s += h[k] * wr[k];
  (sel ? d1s0 : d0s0)[(size_t)u * 1024 + n] = __float2bfloat16(tanhf(s));
}

// ---- decoder: d0 = WG 0-127, d1 = WG 128-255; 4-wave K-split per tile ------
__global__ __launch_bounds__(512, 2) void k_dec(
    const bf16* __restrict__ Wd0, const bf16* __restrict__ Wd1,
    const float* __restrict__ bd0, const float* __restrict__ bd1,
    const bf16* __restrict__ h1seq, bf16* d0seq, bf16* d1seq, unsigned* cnt)
{
  const int wg = blockIdx.x, tid = threadIdx.x;
  const int lane = tid & 63, wave = tid >> 6;
  const int col = lane & 15, kg = lane >> 4, r = col;
  const bool L0 = wg < 128;
  const int grp = wave >> 2, q = wave & 3;
  const int tileIdx = (L0 ? wg : wg - 128) * 2 + grp;    // [0,256)
  const int colp = tileIdx * 16 + col;                   // [0,4096)
  const int j = colp >> 2, g = colp & 3;
  __shared__ f32x4 part[2][3][64];

  short8 breg[16];
#pragma unroll
  for (int i = 0; i < 16; ++i) breg[i] = short8{0,0,0,0,0,0,0,0};
  const int NF = L0 ? 12 : 16;
  if (L0){
    const bf16* W = Wd0 + (size_t)colp * 1536 + q * 384;
#pragma unroll
    for (int i = 0; i < 12; ++i) breg[i] = *(const short8*)(W + i * 32 + kg * 8);
  } else {
    const bf16* W = Wd1 + (size_t)colp * 2048 + q * 512;
#pragma unroll
    for (int i = 0; i < 16; ++i) breg[i] = *(const short8*)(W + i * 32 + kg * 8);
  }
#pragma unroll
  for (int i = 0; i < 16; ++i) asm volatile("" : "+v"(breg[i]));   // pin in VGPRs

  const float bias = L0 ? bd0[colp] : bd1[colp];
  float c_st[4] = {0.f, 0.f, 0.f, 0.f};

  for (int tick = 0; tick < 513; ++tick){
    const int t = tick - (L0 ? 0 : 1);
    const bool active = (t >= 0 && t < 512);
    f32x4 acc = {0.f, 0.f, 0.f, 0.f};
    if (active){
      short8 av[16];
      if (L0){
        const bf16* h1p = h1seq + (size_t)(t + 1) * 16 * 512 + r * 512 + kg * 8;   // static
        const bf16* d0p = d0seq + (size_t)t * 16 * 1024 + r * 1024 + kg * 8;       // dynamic
        if      (q == 0)  ldA<12, false>(h1p, av);
        else if (q == 1){ ldA<4, false>(h1p + 384, av); ldA<8, true>(d0p, av + 4); }
        else if (q == 2)  ldA<12, true>(d0p + 256, av);
        else              ldA<12, true>(d0p + 640, av);
      } else {
        const bf16* d0n = d0seq + (size_t)(t + 1) * 16 * 1024 + r * 1024 + kg * 8; // dynamic
        const bf16* d1c = d1seq + (size_t)t * 16 * 1024 + r * 1024 + kg * 8;       // dynamic
        if      (q == 0) ldA<16, true>(d0n, av);
        else if (q == 1) ldA<16, true>(d0n + 512, av);
        else if (q == 2) ldA<16, true>(d1c, av);
        else             ldA<16, true>(d1c + 512, av);
      }
      asm volatile("s_waitcnt vmcnt(0)" ::: "memory");
      __builtin_amdgcn_sched_barrier(0);
      if (L0){
#pragma unroll
        for (int i = 0; i < 12; ++i)
          acc = __builtin_amdgcn_mfma_f32_16x16x32_bf16(av[i], breg[i], acc, 0, 0, 0);
      } else {
#pragma unroll
        for (int i = 0; i < 16; ++i)
          acc = __builtin_amdgcn_mfma_f32_16x16x32_bf16(av[i], breg[i], acc, 0, 0, 0);
      }
      if (q != 0) part[grp][q - 1][lane] = acc;
    }
    __syncthreads();
    if (active && q == 0){
      f32x4 p0 = part[grp][0][lane], p1 = part[grp][1][lane], p2 = part[grp][2][lane];
      float v[4];
#pragma unroll
      for (int rr = 0; rr < 4; ++rr) v[rr] = acc[rr] + p0[rr] + p1[rr] + p2[rr] + bias;
      bf16* hrow = (L0 ? d0seq : d1seq) + (size_t)(t + 1) * 16 * 1024;
      gates_store(v, c_st, g, kg, j, hrow, 1024, nullptr);
    }
    gbar_arrive(cnt);
    gbar_wait(cnt, 256u * (tick + 1));
  }
  (void)NF;
}

// ---- logits ---------------------------------------------------------------
__global__ __launch_bounds__(256) void k_logits(const bf16* __restrict__ d1seq,
                                                const bf16* __restrict__ ow,
                                                const float* __restrict__ ob,
                                                float* __restrict__ logits)
{
  const int u = blockIdx.x >> 4, tb = blockIdx.x & 15;
  __shared__ bf16 rows[32][1024];
  const int tid = threadIdx.x;
  for (int idx = tid; idx < 4096; idx += 256){
    int tl = idx >> 7, seg = idx & 127;
    *(short8*)&rows[tl][seg * 8] =
      *(const short8*)(d1seq + ((size_t)(tb * 32 + tl + 1) * 16 + u) * 1024 + seg * 8);
  }
  __syncthreads();
  for (int p = tid; p < 512; p += 256){
    int tl = p >> 4, o = p & 15;
    const bf16* wr = ow + (size_t)o * 1024;
    float s = 0.f;
    for (int k = 0; k < 1024; k += 8){
      short8 av = *(const short8*)&rows[tl][k];
      short8 wv = *(const short8*)(wr + k);
#pragma unroll
      for (int e = 0; e < 8; ++e) s += bfraw2f(av[e]) * bfraw2f(wv[e]);
    }
    logits[((size_t)u * 16 + o) * 512 + tb * 32 + tl] = s + ob[o];
  }
}

// ---- softmax over t per (u,o); out[t][u*16+o] ------------------------------
__global__ __launch_bounds__(256) void k_softmax(const float* __restrict__ logits,
                                                 float* __restrict__ out)
{
  const int u = blockIdx.x >> 4, o = blockIdx.x & 15;
  const float* L = logits + ((size_t)u * 16 + o) * 512;
  const int tid = threadIdx.x;
  float v0 = L[tid], v1 = L[tid + 256];
  float m = fmaxf(v0, v1);
  for (int d = 1; d < 64; d <<= 1) m = fmaxf(m, __shfl_xor(m, d));
  __shared__ float red[4], red2[4];
  if ((tid & 63) == 0) red[tid >> 6] = m;
  __syncthreads();
  m = fmaxf(fmaxf(red[0], red[1]), fmaxf(red[2], red[3]));
  float e0 = expf(v0 - m), e1 = expf(v1 - m);
  float s = e0 + e1;
  for (int d = 1; d < 64; d <<= 1) s += __shfl_xor(s, d);
  if ((tid & 63) == 0) red2[tid >> 6] = s;
  __syncthreads();
  s = red2[0] + red2[1] + red2[2] + red2[3];
  float inv = 1.f / s;
  out[(size_t)tid * 256 + u * 16 + o] = e0 * inv;
  out[(size_t)(tid + 256) * 256 + u * 16 + o] = e1 * inv;
}

// ---------------------------------------------------------------------------
extern "C" void kernel_launch(void* const* d_in, const int* in_sizes, int n_in,
                              void* d_out, int out_size, void* d_ws, size_t ws_size,
                              hipStream_t stream)
{
  const float* z      = (const float*)d_in[0];
  const float* fc0_w  = (const float*)d_in[1];
  const float* fc0_b  = (const float*)d_in[2];
  const float* fc1_w  = (const float*)d_in[3];
  const float* fc1_b  = (const float*)d_in[4];
  const float* c_wih0 = (const float*)d_in[5];
  const float* c_whh0 = (const float*)d_in[6];
  const float* c_b0   = (const float*)d_in[7];
  const float* c_wih1 = (const float*)d_in[8];
  const float* c_whh1 = (const float*)d_in[9];
  const float* c_b1   = (const float*)d_in[10];
  const float* d_wih0 = (const float*)d_in[11];
  const float* d_whh0 = (const float*)d_in[12];
  const float* d_b0   = (const float*)d_in[13];
  const float* d_wih1 = (const float*)d_in[14];
  const float* d_whh1 = (const float*)d_in[15];
  const float* d_b1   = (const float*)d_in[16];
  const float* out_w  = (const float*)d_in[17];
  const float* out_b  = (const float*)d_in[18];

  char* p = (char*)d_ws;
  auto alloc = [&](size_t bytes) -> char* {
    char* r = p; p += (bytes + 255) & ~(size_t)255; return r;
  };
  bf16*  Wgx0p  = (bf16*)alloc(2048ull * 512 * 2);
  bf16*  Wc0p   = (bf16*)alloc(2048ull * 512 * 2);
  bf16*  Wc1p   = (bf16*)alloc(2048ull * 1024 * 2);
  bf16*  Wd0p   = (bf16*)alloc(4096ull * 1536 * 2);
  bf16*  Wd1p   = (bf16*)alloc(4096ull * 2048 * 2);
  float* bc0p   = (float*)alloc(2048 * 4);
  float* bc1p   = (float*)alloc(2048 * 4);
  float* bd0p   = (float*)alloc(4096 * 4);
  float* bd1p   = (float*)alloc(4096 * 4);
  bf16*  outwbf = (bf16*)alloc(16384 * 2);
  bf16*  x      = (bf16*)alloc(8192ull * 512 * 2);
  float* gx0    = (float*)alloc(8192ull * 2048 * 4);
  bf16*  h0seq  = (bf16*)alloc(513ull * 16 * 512 * 2);
  bf16*  h1seq  = (bf16*)alloc(513ull * 16 * 512 * 2);
  bf16*  d0seq  = (bf16*)alloc(513ull * 16 * 1024 * 2);
  bf16*  d1seq  = (bf16*)alloc(513ull * 16 * 1024 * 2);
  float* hT0    = (float*)alloc(16 * 512 * 4);
  float* hT1    = (float*)alloc(16 * 512 * 4);
  float* logits = (float*)alloc(16ull * 16 * 512 * 4);
  unsigned* cntC = (unsigned*)alloc(256);
  unsigned* cntD = (unsigned*)alloc(256);
  if ((size_t)(p - (char*)d_ws) > ws_size){
    fprintf(stderr, "kernel_launch: ws too small (%zu needed, %zu given)\n",
            (size_t)(p - (char*)d_ws), ws_size);
    return;
  }

  hipMemsetAsync(cntC, 0, 4, stream);
  hipMemsetAsync(cntD, 0, 4, stream);
  hipMemsetAsync(h0seq, 0, 16 * 512 * 2, stream);
  hipMemsetAsync(h1seq, 0, 16 * 512 * 2, stream);

  k_prep_w<<<2048, 256, 0, stream>>>(c_wih0, nullptr, 512, 0,   512, Wgx0p);
  k_prep_w<<<2048, 256, 0, stream>>>(c_whh0, nullptr, 512, 0,   512, Wc0p);
  k_prep_w<<<2048, 256, 0, stream>>>(c_wih1, c_whh1, 512, 512,  512, Wc1p);
  k_prep_w<<<4096, 256, 0, stream>>>(d_wih0, d_whh0, 512, 1024, 1024, Wd0p);
  k_prep_w<<<4096, 256, 0, stream>>>(d_wih1, d_whh1, 1024, 1024, 1024, Wd1p);
  k_prep_b<<<8,  256, 0, stream>>>(c_b0, 512,  bc0p);
  k_prep_b<<<8,  256, 0, stream>>>(c_b1, 512,  bc1p);
  k_prep_b<<<16, 256, 0, stream>>>(d_b0, 1024, bd0p);
  k_prep_b<<<16, 256, 0, stream>>>(d_b1, 1024, bd1p);
  k_conv_bf<<<64, 256, 0, stream>>>(out_w, outwbf, 16 * 1024);

  k_fc0<<<8192, 256, 0, stream>>>(z, fc0_w, fc0_b, x);
  k_gemm_gx0<<<1024, 256, 0, stream>>>(x, Wgx0p, bc0p, gx0);

  k_cond<<<48, 512, 0, stream>>>(Wc0p, Wc1p, bc1p, gx0, h0seq, h1seq, hT0, hT1, cntC);
  k_hd<<<128, 256, 0, stream>>>(hT0, hT1, fc1_w, fc1_b, d0seq, d1seq);
  k_dec<<<256, 512, 0, stream>>>(Wd0p, Wd1p, bd0p, bd1p, h1seq, d0seq, d1seq, cntD);

  k_logits<<<256, 256, 0, stream>>>(d1seq, outwbf, out_b, logits);
  k_softmax<<<256, 256, 0, stream>>>(logits, (float*)d_out);
}

// Round 3
// 8449.424 us; speedup vs baseline: 3.5188x; 1.0704x over previous
//
#include <hip/hip_runtime.h>
#include <hip/hip_bf16.h>
#include <cstdio>

// ---------------------------------------------------------------------------
// HierarchicalDecoder: 4-layer LSTM stack, T=512, batch U=16.
// Persistent kernels + per-timestep device barrier.
// Protocol v3: writers use sc0 sc1 write-through stores (data lands at the
// coherence point) + vmcnt drain + RELAXED multi-counter arrive; readers use
// PLAIN CACHED loads after a single per-tick acquire-agent fence (buffer_inv)
// so L2/L1 absorb the ~300x cross-WG read redundancy of the h-state.
// ---------------------------------------------------------------------------

typedef __attribute__((ext_vector_type(8))) short short8;   // 8 x bf16
typedef __attribute__((ext_vector_type(4))) float f32x4;
using bf16 = __hip_bfloat16;

__device__ __forceinline__ float bfraw2f(short s){
  return __uint_as_float(((unsigned)(unsigned short)s) << 16);
}

// ---- grid barrier: 16 padded counters, relaxed arrive, acquire-fence wait --
__device__ __forceinline__ void gbar_arrive(unsigned* cnt){
  asm volatile("s_waitcnt vmcnt(0)" ::: "memory");   // h-stores reached IF
  __syncthreads();
  if (threadIdx.x == 0)
    __hip_atomic_fetch_add(&cnt[(blockIdx.x & 15) * 32], 1u,
                           __ATOMIC_RELAXED, __HIP_MEMORY_SCOPE_AGENT);
}
__device__ __forceinline__ void gbar_wait(const unsigned* cnt, unsigned target){
  if (threadIdx.x < 64){
    const int l = threadIdx.x;
    for (;;){
      bool ok = true;
      if (l < 16)
        ok = __hip_atomic_load(&cnt[l * 32], __ATOMIC_RELAXED,
                               __HIP_MEMORY_SCOPE_AGENT) >= target;
      if (__all(ok)) break;
      __builtin_amdgcn_s_sleep(1);
    }
    __builtin_amdgcn_fence(__ATOMIC_ACQUIRE, "agent");  // inv L1+L2 once/tick
  }
  __syncthreads();
}

// ---- A-operand loads: plain cached (fence made them safe) ------------------
template<int N>
__device__ __forceinline__ void ldA(const bf16* base, short8* av){
#pragma unroll
  for (int i = 0; i < N; ++i)
    av[i] = *(const short8*)(base + i * 32);
}

__device__ __forceinline__ void st2_sc1(bf16* p, unsigned v){
  asm volatile("global_store_short %0, %1, off sc0 sc1" :: "v"(p), "v"(v) : "memory");
}

// ---- LSTM gate math; lanes 4j..4j+3 hold gates i,f,g,o of unit j ----------
__device__ __forceinline__ void gates_store(const float v[4], float* c_st, int g,
                                            int kg, int j, bf16* hrow, int Hl,
                                            float* hTp)
{
#pragma unroll
  for (int rr = 0; rr < 4; ++rr){
    float a = (g == 2) ? tanhf(v[rr]) : 1.f / (1.f + expf(-v[rr]));
    float x1 = __shfl_xor(a, 1);
    float x2 = __shfl_xor(a, 2);
    float x3 = __shfl_xor(x1, 2);
    float cn = x1 * c_st[rr] + a * x2;   // on g==0 lanes: sig(f)*c + sig(i)*tanh(g)
    float hn = x3 * tanhf(cn);           // sig(o)*tanh(c)
    c_st[rr] = cn;
    if (g == 0){
      int u = kg * 4 + rr;
      bf16 hb = __float2bfloat16(hn);
      unsigned us = *reinterpret_cast<unsigned short*>(&hb);
      st2_sc1(hrow + (size_t)u * Hl + j, us);
      if (hTp) hTp[(size_t)u * Hl + j] = hn;
    }
  }
}

// ---- weight prep: permute rows to col'=4j+g, concat K, cvt bf16 ------------
__global__ void k_prep_w(const float* __restrict__ srcA, const float* __restrict__ srcB,
                         int K1, int K2, int H, bf16* __restrict__ dst)
{
  const int row = blockIdx.x;            // col' in [0, 4H)
  const int j = row >> 2, g = row & 3;
  const int Kt = K1 + K2;
  const float* sA = srcA + (size_t)(g * H + j) * K1;
  const float* sB = srcB ? srcB + (size_t)(g * H + j) * K2 : nullptr;
  bf16* d = dst + (size_t)row * Kt;
  for (int k = threadIdx.x; k < Kt; k += blockDim.x)
    d[k] = __float2bfloat16(k < K1 ? sA[k] : sB[k - K1]);
}

__global__ void k_prep_b(const float* __restrict__ src, int H, float* __restrict__ dst){
  int i = blockIdx.x * blockDim.x + threadIdx.x;
  if (i < 4 * H) dst[i] = src[(i & 3) * H + (i >> 2)];
}

__global__ void k_conv_bf(const float* __restrict__ src, bf16* __restrict__ dst, int n){
  int i = blockIdx.x * blockDim.x + threadIdx.x;
  if (i < n) dst[i] = __float2bfloat16(src[i]);
}

// ---- fc0 -------------------------------------------------------------------
__global__ void k_fc0(const float* __restrict__ z, const float* __restrict__ w,
                      const float* __restrict__ b, bf16* __restrict__ x)
{
  const int m = blockIdx.x;              // t*16+u
  const int t = m >> 4, u = m & 15;
  const float* zr = z + (size_t)t * 512 + u * 32;
  float zv[32];
#pragma unroll
  for (int k = 0; k < 32; ++k) zv[k] = zr[k];
  for (int n = threadIdx.x; n < 512; n += 256){
    const float* wr = w + n * 32;
    float s = b[n];
#pragma unroll
    for (int k = 0; k < 32; ++k) s += zv[k] * wr[k];
    x[(size_t)m * 512 + n] = __float2bfloat16(tanhf(s));
  }
}

// ---- big GEMM for gx0 = x @ Wgx0'^T + bc0' ---------------------------------
__device__ __forceinline__ void gload16(const void* g, void* lds_wave_base){
  __builtin_amdgcn_global_load_lds((const __attribute__((address_space(1))) void*)g,
                                   (__attribute__((address_space(3))) void*)lds_wave_base,
                                   16, 0, 0);
}

__global__ __launch_bounds__(256) void k_gemm_gx0(const bf16* __restrict__ A,
                                                  const bf16* __restrict__ W,
                                                  const float* __restrict__ bias,
                                                  float* __restrict__ C)
{
  __shared__ bf16 Al[128 * 64];
  __shared__ bf16 Bl[128 * 64];
  const int tid = threadIdx.x, lane = tid & 63, wave = tid >> 6;
  const int bm = blockIdx.x & 63, bn = blockIdx.x >> 6;
  const int wm = wave >> 1, wn = wave & 1;
  const int col = lane & 15, kg = lane >> 4;

  f32x4 acc[4][4];
#pragma unroll
  for (int i = 0; i < 4; ++i)
#pragma unroll
    for (int q = 0; q < 4; ++q) acc[i][q] = f32x4{0.f, 0.f, 0.f, 0.f};

  const int r = tid >> 3, c8 = (tid & 7) * 8;
  for (int k0 = 0; k0 < 512; k0 += 64){
    const bf16* ga = A + (size_t)(bm * 128 + r) * 512 + k0 + c8;
    const bf16* gb = W + (size_t)(bn * 128 + r) * 512 + k0 + c8;
#pragma unroll
    for (int i = 0; i < 4; ++i){
      gload16(ga + (size_t)32 * i * 512, (char*)Al + (size_t)i * 4096 + wave * 1024);
      gload16(gb + (size_t)32 * i * 512, (char*)Bl + (size_t)i * 4096 + wave * 1024);
    }
    __syncthreads();
#pragma unroll
    for (int kb = 0; kb < 2; ++kb){
      short8 af[4], bfr[4];
#pragma unroll
      for (int i = 0; i < 4; ++i)
        af[i] = *(const short8*)&Al[(wm * 64 + i * 16 + col) * 64 + kb * 32 + kg * 8];
#pragma unroll
      for (int i = 0; i < 4; ++i)
        bfr[i] = *(const short8*)&Bl[(wn * 64 + i * 16 + col) * 64 + kb * 32 + kg * 8];
#pragma unroll
      for (int i = 0; i < 4; ++i)
#pragma unroll
        for (int q = 0; q < 4; ++q)
          acc[i][q] = __builtin_amdgcn_mfma_f32_16x16x32_bf16(af[i], bfr[q], acc[i][q], 0, 0, 0);
    }
    __syncthreads();
  }
#pragma unroll
  for (int i = 0; i < 4; ++i)
#pragma unroll
    for (int q = 0; q < 4; ++q){
      int cc = bn * 128 + wn * 64 + q * 16 + col;
      float bv = bias[cc];
#pragma unroll
      for (int rr = 0; rr < 4; ++rr){
        int rrow = bm * 128 + wm * 64 + i * 16 + kg * 4 + rr;
        C[(size_t)rrow * 2048 + cc] = acc[i][q][rr] + bv;
      }
    }
}

// ---- conductor: L0 = WG 0-15 (1 wave/tile), L1 = WG 16-47 (wave pairs) -----
__global__ __launch_bounds__(512, 2) void k_cond(
    const bf16* __restrict__ Wc0, const bf16* __restrict__ Wc1,
    const float* __restrict__ bc1, const float* __restrict__ gx0,
    bf16* h0seq, bf16* h1seq, float* hT0, float* hT1, unsigned* cnt)
{
  const int wg = blockIdx.x, tid = threadIdx.x;
  const int lane = tid & 63, wave = tid >> 6;
  const int col = lane & 15, kg = lane >> 4;
  const int r = col;                         // batch row (u) for the A operand
  const bool L0 = wg < 16;
  __shared__ f32x4 part[4][64];

  int tileIdx, half = 0;
  if (L0) tileIdx = wg * 8 + wave;                       // [0,128)
  else  { tileIdx = (wg - 16) * 4 + (wave >> 1); half = wave & 1; }
  const int colp = tileIdx * 16 + col;                   // [0,2048)
  const int j = colp >> 2, g = colp & 3;

  short8 breg[16];
  {
    const bf16* W = L0 ? (Wc0 + (size_t)colp * 512)
                       : (Wc1 + (size_t)colp * 1024 + half * 512);
#pragma unroll
    for (int i = 0; i < 16; ++i) breg[i] = *(const short8*)(W + i * 32 + kg * 8);
  }
#pragma unroll
  for (int i = 0; i < 16; ++i) asm volatile("" : "+v"(breg[i]));   // pin in VGPRs

  const float bias = L0 ? 0.f : bc1[colp];
  float c_st[4] = {0.f, 0.f, 0.f, 0.f};
  float gxv[4];
  if (L0){
#pragma unroll
    for (int rr = 0; rr < 4; ++rr)
      gxv[rr] = gx0[((size_t)(kg * 4 + rr)) * 2048 + colp];        // t = 0
  }

  for (int tick = 0; tick < 513; ++tick){
    const int t = tick - (L0 ? 0 : 1);
    const bool active = (t >= 0 && t < 512);
    f32x4 acc = {0.f, 0.f, 0.f, 0.f};
    if (active){
      short8 av[16];
      const bf16* base;
      if (L0)             base = h0seq + (size_t)t * 16 * 512 + r * 512 + kg * 8;
      else if (half == 0) base = h0seq + (size_t)(t + 1) * 16 * 512 + r * 512 + kg * 8;
      else                base = h1seq + (size_t)t * 16 * 512 + r * 512 + kg * 8;
      ldA<16>(base, av);
      asm volatile("s_waitcnt vmcnt(0)" ::: "memory");
      __builtin_amdgcn_sched_barrier(0);
#pragma unroll
      for (int i = 0; i < 16; ++i)
        acc = __builtin_amdgcn_mfma_f32_16x16x32_bf16(av[i], breg[i], acc, 0, 0, 0);
      if (!L0 && half == 1) part[wave >> 1][lane] = acc;
    }
    if (!L0) __syncthreads();                            // uniform per WG
    if (active && (L0 || half == 0)){
      float v[4];
      if (L0){
#pragma unroll
        for (int rr = 0; rr < 4; ++rr) v[rr] = acc[rr] + gxv[rr];  // gx0 has bias
      } else {
        f32x4 p2 = part[wave >> 1][lane];
#pragma unroll
        for (int rr = 0; rr < 4; ++rr) v[rr] = acc[rr] + p2[rr] + bias;
      }
      bf16* hrow = (L0 ? h0seq : h1seq) + (size_t)(t + 1) * 16 * 512;
      float* hTp = (t == 511) ? (L0 ? hT0 : hT1) : nullptr;
      gates_store(v, c_st, g, kg, j, hrow, 512, hTp);
    }
    gbar_arrive(cnt);
    if (L0 && tick + 1 < 512){                           // prefetch gx0 for next t
#pragma unroll
      for (int rr = 0; rr < 4; ++rr)
        gxv[rr] = gx0[((size_t)(tick + 1) * 16 + kg * 4 + rr) * 2048 + colp];
    }
    gbar_wait(cnt, 3u * (tick + 1));                     // 48 WGs / 16 counters
  }
}

// ---- hd0/hd1 = tanh(fc1(hT)) into decoder seq slot 0 -----------------------
__global__ void k_hd(const float* __restrict__ hT0, const float* __restrict__ hT1,
                     const float* __restrict__ w, const float* __restrict__ b,
                     bf16* __restrict__ d0s0, bf16* __restrict__ d1s0)
{
  int gid = blockIdx.x * 256 + threadIdx.x;       // 32768
  int sel = gid >> 14;
  int u = (gid >> 10) & 15, n = gid & 1023;
  const float* h = (sel ? hT1 : hT0) + u * 512;
  const float* wr = w + (size_t)n * 512;
  float s = b[n];
  for (int k = 0; k < 512; ++k) s += h[k] * wr[k];
  (sel ? d1s0 : d0s0)[(size_t)u * 1024 + n] = __float2bfloat16(tanhf(s));
}

// ---- decoder: d0 = WG 0-127, d1 = WG 128-255; 4-wave K-split per tile ------
__global__ __launch_bounds__(512, 2) void k_dec(
    const bf16* __restrict__ Wd0, const bf16* __restrict__ Wd1,
    const float* __restrict__ bd0, const float* __restrict__ bd1,
    const bf16* __restrict__ h1seq, bf16* d0seq, bf16* d1seq, unsigned* cnt)
{
  const int wg = blockIdx.x, tid = threadIdx.x;
  const int lane = tid & 63, wave = tid >> 6;
  const int col = lane & 15, kg = lane >> 4, r = col;
  const bool L0 = wg < 128;
  const int grp = wave >> 2, q = wave & 3;
  const int tileIdx = (L0 ? wg : wg - 128) * 2 + grp;    // [0,256)
  const int colp = tileIdx * 16 + col;                   // [0,4096)
  const int j = colp >> 2, g = colp & 3;
  __shared__ f32x4 part[2][3][64];

  short8 breg[16];
#pragma unroll
  for (int i = 0; i < 16; ++i) breg[i] = short8{0,0,0,0,0,0,0,0};
  if (L0){
    const bf16* W = Wd0 + (size_t)colp * 1536 + q * 384;
#pragma unroll
    for (int i = 0; i < 12; ++i) breg[i] = *(const short8*)(W + i * 32 + kg * 8);
  } else {
    const bf16* W = Wd1 + (size_t)colp * 2048 + q * 512;
#pragma unroll
    for (int i = 0; i < 16; ++i) breg[i] = *(const short8*)(W + i * 32 + kg * 8);
  }
#pragma unroll
  for (int i = 0; i < 16; ++i) asm volatile("" : "+v"(breg[i]));   // pin in VGPRs

  const float bias = L0 ? bd0[colp] : bd1[colp];
  float c_st[4] = {0.f, 0.f, 0.f, 0.f};

  for (int tick = 0; tick < 513; ++tick){
    const int t = tick - (L0 ? 0 : 1);
    const bool active = (t >= 0 && t < 512);
    f32x4 acc = {0.f, 0.f, 0.f, 0.f};
    if (active){
      short8 av[16];
      if (L0){
        const bf16* h1p = h1seq + (size_t)(t + 1) * 16 * 512 + r * 512 + kg * 8;
        const bf16* d0p = d0seq + (size_t)t * 16 * 1024 + r * 1024 + kg * 8;
        if      (q == 0)  ldA<12>(h1p, av);
        else if (q == 1){ ldA<4>(h1p + 384, av); ldA<8>(d0p, av + 4); }
        else if (q == 2)  ldA<12>(d0p + 256, av);
        else              ldA<12>(d0p + 640, av);
      } else {
        const bf16* d0n = d0seq + (size_t)(t + 1) * 16 * 1024 + r * 1024 + kg * 8;
        const bf16* d1c = d1seq + (size_t)t * 16 * 1024 + r * 1024 + kg * 8;
        if      (q == 0) ldA<16>(d0n, av);
        else if (q == 1) ldA<16>(d0n + 512, av);
        else if (q == 2) ldA<16>(d1c, av);
        else             ldA<16>(d1c + 512, av);
      }
      asm volatile("s_waitcnt vmcnt(0)" ::: "memory");
      __builtin_amdgcn_sched_barrier(0);
      if (L0){
#pragma unroll
        for (int i = 0; i < 12; ++i)
          acc = __builtin_amdgcn_mfma_f32_16x16x32_bf16(av[i], breg[i], acc, 0, 0, 0);
      } else {
#pragma unroll
        for (int i = 0; i < 16; ++i)
          acc = __builtin_amdgcn_mfma_f32_16x16x32_bf16(av[i], breg[i], acc, 0, 0, 0);
      }
      if (q != 0) part[grp][q - 1][lane] = acc;
    }
    __syncthreads();
    if (active && q == 0){
      f32x4 p0 = part[grp][0][lane], p1 = part[grp][1][lane], p2 = part[grp][2][lane];
      float v[4];
#pragma unroll
      for (int rr = 0; rr < 4; ++rr) v[rr] = acc[rr] + p0[rr] + p1[rr] + p2[rr] + bias;
      bf16* hrow = (L0 ? d0seq : d1seq) + (size_t)(t + 1) * 16 * 1024;
      gates_store(v, c_st, g, kg, j, hrow, 1024, nullptr);
    }
    gbar_arrive(cnt);
    gbar_wait(cnt, 16u * (tick + 1));                    // 256 WGs / 16 counters
  }
}

// ---- logits ---------------------------------------------------------------
__global__ __launch_bounds__(256) void k_logits(const bf16* __restrict__ d1seq,
                                                const bf16* __restrict__ ow,
                                                const float* __restrict__ ob,
                                                float* __restrict__ logits)
{
  const int u = blockIdx.x >> 4, tb = blockIdx.x & 15;
  __shared__ bf16 rows[32][1024];
  const int tid = threadIdx.x;
  for (int idx = tid; idx < 4096; idx += 256){
    int tl = idx >> 7, seg = idx & 127;
    *(short8*)&rows[tl][seg * 8] =
      *(const short8*)(d1seq + ((size_t)(tb * 32 + tl + 1) * 16 + u) * 1024 + seg * 8);
  }
  __syncthreads();
  for (int p = tid; p < 512; p += 256){
    int tl = p >> 4, o = p & 15;
    const bf16* wr = ow + (size_t)o * 1024;
    float s = 0.f;
    for (int k = 0; k < 1024; k += 8){
      short8 av = *(const short8*)&rows[tl][k];
      short8 wv = *(const short8*)(wr + k);
#pragma unroll
      for (int e = 0; e < 8; ++e) s += bfraw2f(av[e]) * bfraw2f(wv[e]);
    }
    logits[((size_t)u * 16 + o) * 512 + tb * 32 + tl] = s + ob[o];
  }
}

// ---- softmax over t per (u,o); out[t][u*16+o] ------------------------------
__global__ __launch_bounds__(256) void k_softmax(const float* __restrict__ logits,
                                                 float* __restrict__ out)
{
  const int u = blockIdx.x >> 4, o = blockIdx.x & 15;
  const float* L = logits + ((size_t)u * 16 + o) * 512;
  const int tid = threadIdx.x;
  float v0 = L[tid], v1 = L[tid + 256];
  float m = fmaxf(v0, v1);
  for (int d = 1; d < 64; d <<= 1) m = fmaxf(m, __shfl_xor(m, d));
  __shared__ float red[4], red2[4];
  if ((tid & 63) == 0) red[tid >> 6] = m;
  __syncthreads();
  m = fmaxf(fmaxf(red[0], red[1]), fmaxf(red[2], red[3]));
  float e0 = expf(v0 - m), e1 = expf(v1 - m);
  float s = e0 + e1;
  for (int d = 1; d < 64; d <<= 1) s += __shfl_xor(s, d);
  if ((tid & 63) == 0) red2[tid >> 6] = s;
  __syncthreads();
  s = red2[0] + red2[1] + red2[2] + red2[3];
  float inv = 1.f / s;
  out[(size_t)tid * 256 + u * 16 + o] = e0 * inv;
  out[(size_t)(tid + 256) * 256 + u * 16 + o] = e1 * inv;
}

// ---------------------------------------------------------------------------
extern "C" void kernel_launch(void* const* d_in, const int* in_sizes, int n_in,
                              void* d_out, int out_size, void* d_ws, size_t ws_size,
                              hipStream_t stream)
{
  const float* z      = (const float*)d_in[0];
  const float* fc0_w  = (const float*)d_in[1];
  const float* fc0_b  = (const float*)d_in[2];
  const float* fc1_w  = (const float*)d_in[3];
  const float* fc1_b  = (const float*)d_in[4];
  const float* c_wih0 = (const float*)d_in[5];
  const float* c_whh0 = (const float*)d_in[6];
  const float* c_b0   = (const float*)d_in[7];
  const float* c_wih1 = (const float*)d_in[8];
  const float* c_whh1 = (const float*)d_in[9];
  const float* c_b1   = (const float*)d_in[10];
  const float* d_wih0 = (const float*)d_in[11];
  const float* d_whh0 = (const float*)d_in[12];
  const float* d_b0   = (const float*)d_in[13];
  const float* d_wih1 = (const float*)d_in[14];
  const float* d_whh1 = (const float*)d_in[15];
  const float* d_b1   = (const float*)d_in[16];
  const float* out_w  = (const float*)d_in[17];
  const float* out_b  = (const float*)d_in[18];

  char* p = (char*)d_ws;
  auto alloc = [&](size_t bytes) -> char* {
    char* r = p; p += (bytes + 255) & ~(size_t)255; return r;
  };
  bf16*  Wgx0p  = (bf16*)alloc(2048ull * 512 * 2);
  bf16*  Wc0p   = (bf16*)alloc(2048ull * 512 * 2);
  bf16*  Wc1p   = (bf16*)alloc(2048ull * 1024 * 2);
  bf16*  Wd0p   = (bf16*)alloc(4096ull * 1536 * 2);
  bf16*  Wd1p   = (bf16*)alloc(4096ull * 2048 * 2);
  float* bc0p   = (float*)alloc(2048 * 4);
  float* bc1p   = (float*)alloc(2048 * 4);
  float* bd0p   = (float*)alloc(4096 * 4);
  float* bd1p   = (float*)alloc(4096 * 4);
  bf16*  outwbf = (bf16*)alloc(16384 * 2);
  bf16*  x      = (bf16*)alloc(8192ull * 512 * 2);
  float* gx0    = (float*)alloc(8192ull * 2048 * 4);
  bf16*  h0seq  = (bf16*)alloc(513ull * 16 * 512 * 2);
  bf16*  h1seq  = (bf16*)alloc(513ull * 16 * 512 * 2);
  bf16*  d0seq  = (bf16*)alloc(513ull * 16 * 1024 * 2);
  bf16*  d1seq  = (bf16*)alloc(513ull * 16 * 1024 * 2);
  float* hT0    = (float*)alloc(16 * 512 * 4);
  float* hT1    = (float*)alloc(16 * 512 * 4);
  float* logits = (float*)alloc(16ull * 16 * 512 * 4);
  unsigned* cntC = (unsigned*)alloc(16 * 32 * 4);
  unsigned* cntD = (unsigned*)alloc(16 * 32 * 4);
  if ((size_t)(p - (char*)d_ws) > ws_size){
    fprintf(stderr, "kernel_launch: ws too small (%zu needed, %zu given)\n",
            (size_t)(p - (char*)d_ws), ws_size);
    return;
  }

  hipMemsetAsync(cntC, 0, 16 * 32 * 4, stream);
  hipMemsetAsync(cntD, 0, 16 * 32 * 4, stream);
  hipMemsetAsync(h0seq, 0, 16 * 512 * 2, stream);
  hipMemsetAsync(h1seq, 0, 16 * 512 * 2, stream);

  k_prep_w<<<2048, 256, 0, stream>>>(c_wih0, nullptr, 512, 0,   512, Wgx0p);
  k_prep_w<<<2048, 256, 0, stream>>>(c_whh0, nullptr, 512, 0,   512, Wc0p);
  k_prep_w<<<2048, 256, 0, stream>>>(c_wih1, c_whh1, 512, 512,  512, Wc1p);
  k_prep_w<<<4096, 256, 0, stream>>>(d_wih0, d_whh0, 512, 1024, 1024, Wd0p);
  k_prep_w<<<4096, 256, 0, stream>>>(d_wih1, d_whh1, 1024, 1024, 1024, Wd1p);
  k_prep_b<<<8,  256, 0, stream>>>(c_b0, 512,  bc0p);
  k_prep_b<<<8,  256, 0, stream>>>(c_b1, 512,  bc1p);
  k_prep_b<<<16, 256, 0, stream>>>(d_b0, 1024, bd0p);
  k_prep_b<<<16, 256, 0, stream>>>(d_b1, 1024, bd1p);
  k_conv_bf<<<64, 256, 0, stream>>>(out_w, outwbf, 16 * 1024);

  k_fc0<<<8192, 256, 0, stream>>>(z, fc0_w, fc0_b, x);
  k_gemm_gx0<<<1024, 256, 0, stream>>>(x, Wgx0p, bc0p, gx0);

  k_cond<<<48, 512, 0, stream>>>(Wc0p, Wc1p, bc1p, gx0, h0seq, h1seq, hT0, hT1, cntC);
  k_hd<<<128, 256, 0, stream>>>(hT0, hT1, fc1_w, fc1_b, d0seq, d1seq);
  k_dec<<<256, 512, 0, stream>>>(Wd0p, Wd1p, bd0p, bd1p, h1seq, d0seq, d1seq, cntD);

  k_logits<<<256, 256, 0, stream>>>(d1seq, outwbf, out_b, logits);
  k_softmax<<<256, 256, 0, stream>>>(logits, (float*)d_out);
}